// Round 2
// baseline (9202.595 us; speedup 1.0000x reference)
//
#include <hip/hip_runtime.h>

typedef __attribute__((ext_vector_type(8))) short short8;
typedef __attribute__((ext_vector_type(4))) float f32x4;

#define TT 512
#define II 512
#define HH 1024

// workspace layout (bytes) — identical footprint to previous version
#define OFF_FLAGS  0u          // 512 blk x 16 B (4 wave-flags x 4 B) = 8192
#define OFF_HPACK  8192u       // 2 parity x 8 group x 32 KB = 524288
#define OFF_XPACK  532480u     // 512 t x 4096 frag x 16 B = 33554432
#define OFF_WPACK  34086912u   // 2 dir x 256 cg x 48 ks x 64 lane x 16 B = 25165824
#define OFF_BIAS   59252736u   // 2 x 4096 fp32 = 32768
#define ZERO_BYTES 532480u     // flags + hpack (h0 = 0)

__device__ __forceinline__ unsigned short f2bf(float f) {
  unsigned u = __builtin_bit_cast(unsigned, f);
  u += 0x7FFFu + ((u >> 16) & 1u);   // RNE
  return (unsigned short)(u >> 16);
}
__device__ __forceinline__ float sigm(float x) {
  return __fdividef(1.f, 1.f + __expf(-x));
}
__device__ __forceinline__ float tanh_(float x) {
  return 1.f - __fdividef(2.f, __expf(2.f * x) + 1.f);
}

__global__ void pack_x_kernel(const float* __restrict__ x, short* __restrict__ xpack) {
  int g = blockIdx.x * 256 + threadIdx.x;
  int lane = g & 63;
  int mt = (g >> 6) & 3;
  int ks = (g >> 8) & 15;
  int t = g >> 12;
  int b = mt * 16 + (lane & 15);
  int i = ks * 32 + ((lane >> 4) & 3) * 8;
  const float* src = x + ((size_t)b * TT + t) * II + i;
  float4 v0 = *(const float4*)(src);
  float4 v1 = *(const float4*)(src + 4);
  short8 o;
  o[0] = (short)f2bf(v0.x); o[1] = (short)f2bf(v0.y);
  o[2] = (short)f2bf(v0.z); o[3] = (short)f2bf(v0.w);
  o[4] = (short)f2bf(v1.x); o[5] = (short)f2bf(v1.y);
  o[6] = (short)f2bf(v1.z); o[7] = (short)f2bf(v1.w);
  *(short8*)(xpack + (size_t)g * 8) = o;
}

__global__ void pack_w_kernel(const float* __restrict__ wih_f, const float* __restrict__ whh_f,
                              const float* __restrict__ wih_b, const float* __restrict__ whh_b,
                              short* __restrict__ wpack) {
  int g = blockIdx.x * 256 + threadIdx.x;
  int lane = g & 63;
  int gg = g >> 6;
  int dir = gg / 12288;
  int rem = gg - dir * 12288;
  int cg = rem / 48;
  int ks = rem - cg * 48;
  int col = cg * 16 + (lane & 15);
  int k = ks * 32 + ((lane >> 4) & 3) * 8;
  const float* wih = dir ? wih_b : wih_f;
  const float* whh = dir ? whh_b : whh_f;
  const float* src = (k < II) ? (wih + (size_t)col * II + k)
                              : (whh + (size_t)col * HH + (k - II));
  float4 v0 = *(const float4*)(src);
  float4 v1 = *(const float4*)(src + 4);
  short8 o;
  o[0] = (short)f2bf(v0.x); o[1] = (short)f2bf(v0.y);
  o[2] = (short)f2bf(v0.z); o[3] = (short)f2bf(v0.w);
  o[4] = (short)f2bf(v1.x); o[5] = (short)f2bf(v1.y);
  o[6] = (short)f2bf(v1.z); o[7] = (short)f2bf(v1.w);
  *(short8*)(wpack + (size_t)g * 8) = o;
}

__global__ void pack_bias_kernel(const float* __restrict__ bif, const float* __restrict__ bhf,
                                 const float* __restrict__ bib, const float* __restrict__ bhb,
                                 float* __restrict__ bias) {
  int g = blockIdx.x * 256 + threadIdx.x;
  int dir = g >> 12, n = g & 4095;
  bias[g] = dir ? (bib[n] + bhb[n]) : (bif[n] + bhf[n]);
}

// 512 blocks x 256 threads, 2 blocks/CU. Batch-partitioned recurrences:
// group = (dir, bg) over 4 batch-groups of 16 rows -> 8 INDEPENDENT recurrences.
// Each group has 64 blocks (jgrp = 16 h-cols each); h-exchange payload per
// block is its group's 16x1024 bf16 state = 32 KB (was 128 KB).
// Per block: mt=1, 4 gate-tiles, K split over 4 waves (x: 4 kfr, h: 8 kfr).
// Union-of-waitsets: the 4 waves together wait on all 64 group blocks =
// exactly this block's consumers; h-stores are behind the single barrier, so
// the t+1-overwrite-vs-t-read hazard is excluded as before.
__launch_bounds__(256, 2)
__global__ void lstm_main(const short* __restrict__ xpack, const short* __restrict__ wpack,
                          const float* __restrict__ bias, short* __restrict__ hpack,
                          unsigned* __restrict__ flags, float* __restrict__ out) {
  // red[par][wv*4+g][col 16][row 16] : b128 writes uniform over banks,
  // reads lane-consecutive -> conflict-free. 32 KB (2 blocks/CU = 64 KB).
  __shared__ float red[2 * 16 * 16 * 16];

  const int tid = threadIdx.x;
  const int wv = tid >> 6, lane = tid & 63;
  const int blk = blockIdx.x;
  const int grp = blk >> 6, jgrp = blk & 63;
  const int dir = grp & 1, bg = grp >> 1;
  const int w4 = wv * 4, w8 = wv * 8;

  // ---- preload B fragments (persist across the whole time loop) ----
  short8 bfr[4][12];
  {
    const short8* wp = (const short8*)wpack;
    #pragma unroll
    for (int gg = 0; gg < 4; ++gg) {
      size_t base = ((size_t)(dir * 256 + gg * 64 + jgrp) * 48) * 64 + lane;
      #pragma unroll
      for (int i = 0; i < 4; ++i)
        bfr[gg][i] = wp[base + (size_t)(w4 + i) * 64];
      #pragma unroll
      for (int i = 0; i < 8; ++i)
        bfr[gg][4 + i] = wp[base + (size_t)(16 + w8 + i) * 64];
    }
  }

  const short8* xp8 = (const short8*)xpack;
  const short8* hp8 = (const short8*)hpack;

  // elementwise mapping: thread -> (row b = tid&15, col j = tid>>4); 1 output.
  const int b_loc = tid & 15, j_loc = tid >> 4;
  const int J = jgrp * 16 + j_loc;            // group-local h-col (0..1023)
  const int b_glob = bg * 16 + b_loc;
  float bia[4];
  #pragma unroll
  for (int g = 0; g < 4; ++g) bia[g] = bias[dir * 4096 + g * 1024 + J];
  float c_reg = 0.f;

  // flags: 4 dwords per block. wave wv of this block publishes cols
  // [jgrp*16 + 4wv, +4). Consumer wave wv reads h kfr [8wv,8wv+8) = cols
  // [256wv,+256) -> producers jgrp_p in [16wv,16wv+16) x 4 waves = 64 flags.
  unsigned* myflag = flags + (size_t)blk * 4 + wv;
  const unsigned* wflag =
      flags + (size_t)(grp * 64 + (wv * 16 + (lane >> 2))) * 4 + (lane & 3);

  for (int t = 0; t < TT; ++t) {
    const int par = t & 1;
    const int t_x = dir ? (TT - 1 - t) : t;

    f32x4 acc[4];
    #pragma unroll
    for (int gg = 0; gg < 4; ++gg) acc[gg] = (f32x4){0.f, 0.f, 0.f, 0.f};

    {  // x-part: 4 loads (this group's batch slice), then 16 MFMAs
      const short8* xbase = xp8 + (size_t)t_x * 4096 + bg * 64 + lane;
      short8 xa[4];
      #pragma unroll
      for (int i = 0; i < 4; ++i) xa[i] = xbase[(w4 + i) * 256];
      #pragma unroll
      for (int i = 0; i < 4; ++i)
        #pragma unroll
        for (int gg = 0; gg < 4; ++gg)
          acc[gg] = __builtin_amdgcn_mfma_f32_16x16x32_bf16(xa[i], bfr[gg][i], acc[gg], 0, 0, 0);
    }

    // ---- per-wave wait: 16 producer blocks x 4 waves of my group ----
    if (t) {
      unsigned v = __hip_atomic_load(wflag, __ATOMIC_RELAXED, __HIP_MEMORY_SCOPE_AGENT);
      while (!__all((int)(v >= (unsigned)t))) {
        __builtin_amdgcn_s_sleep(1);
        v = __hip_atomic_load(wflag, __ATOMIC_RELAXED, __HIP_MEMORY_SCOPE_AGENT);
      }
      __builtin_amdgcn_fence(__ATOMIC_ACQUIRE, "agent");  // buffer_inv
    }

    {  // h-part: batch all 8 loads (one far-cache latency), then 32 MFMAs
      const short8* hbase = hp8 + (size_t)(par * 8 + grp) * 2048 + lane;
      short8 ha[8];
      #pragma unroll
      for (int i = 0; i < 8; ++i) ha[i] = hbase[(w8 + i) * 64];
      #pragma unroll
      for (int i = 0; i < 8; ++i)
        #pragma unroll
        for (int gg = 0; gg < 4; ++gg)
          acc[gg] = __builtin_amdgcn_mfma_f32_16x16x32_bf16(ha[i], bfr[gg][4 + i], acc[gg], 0, 0, 0);
    }

    {  // partial sums -> LDS: red[par][w4+gg][col=lane&15][row=q*4..+3]
      int q = lane >> 4, cl = lane & 15;
      float* rb = red + (size_t)par * 4096;
      #pragma unroll
      for (int gg = 0; gg < 4; ++gg)
        *(f32x4*)&rb[((w4 + gg) * 16 + cl) * 16 + q * 4] = acc[gg];
    }
    __syncthreads();   // the ONLY barrier per step

    // ---- elementwise: 1 output per thread ----
    const float* rbr = red + (size_t)par * 4096;
    float g4[4];
    #pragma unroll
    for (int g = 0; g < 4; ++g) g4[g] = bia[g];
    #pragma unroll
    for (int w = 0; w < 4; ++w)
      #pragma unroll
      for (int g = 0; g < 4; ++g)
        g4[g] += rbr[((w * 4 + g) * 16 + j_loc) * 16 + b_loc];

    float cn = sigm(g4[1]) * c_reg + sigm(g4[0]) * tanh_(g4[2]);
    c_reg = cn;
    float h_v = sigm(g4[3]) * tanh_(cn);
    float h_p = __shfl_xor(h_v, 16);     // partner col (j_loc ^ 1), same wave

    const bool evenj = (j_loc & 1) == 0;
    if (evenj) {
      // h -> hpack (A-frag layout, next parity) as one packed dword
      int kfr = J >> 5;
      int lane_ = b_loc | (((J >> 3) & 3) << 4);
      size_t hidx = (size_t)((par ^ 1) * 8 + grp) * 16384 +
                    (size_t)(kfr * 64 + lane_) * 8 + (J & 7);
      unsigned hv = (unsigned)f2bf(h_v) | ((unsigned)f2bf(h_p) << 16);
      __hip_atomic_store((unsigned*)(hpack + hidx), hv, __ATOMIC_RELAXED, __HIP_MEMORY_SCOPE_AGENT);
    }

    // ---- per-wave publish: drain OWN stores, then flag. No barrier. ----
    asm volatile("s_waitcnt vmcnt(0)" ::: "memory");
    if (lane == 0)
      __hip_atomic_store(myflag, (unsigned)(t + 1), __ATOMIC_RELAXED, __HIP_MEMORY_SCOPE_AGENT);
    asm volatile("" ::: "memory");   // keep out-stores below the flag

    // ---- out stores AFTER publish (retire during next step's wait) ----
    if (evenj)
      *(float2*)(out + ((size_t)(b_glob * TT + t) * 2 + dir) * 1024 + J) =
          make_float2(h_v, h_p);
    if (t == TT - 1) {
      float c_p = __shfl_xor(c_reg, 16);
      if (evenj) {
        size_t base2 = (size_t)64 * TT * 2048;
        *(float2*)(out + base2 + (size_t)dir * 131072 + (size_t)b_glob * 1024 + J) =
            make_float2(h_v, h_p);
        *(float2*)(out + base2 + (size_t)dir * 131072 + 65536 + (size_t)b_glob * 1024 + J) =
            make_float2(c_reg, c_p);
      }
    }
  }
}

extern "C" void kernel_launch(void* const* d_in, const int* in_sizes, int n_in,
                              void* d_out, int out_size, void* d_ws, size_t ws_size,
                              hipStream_t stream) {
  const float* x     = (const float*)d_in[0];
  const float* wih_f = (const float*)d_in[1];
  const float* whh_f = (const float*)d_in[2];
  const float* bih_f = (const float*)d_in[3];
  const float* bhh_f = (const float*)d_in[4];
  const float* wih_b = (const float*)d_in[5];
  const float* whh_b = (const float*)d_in[6];
  const float* bih_b = (const float*)d_in[7];
  const float* bhh_b = (const float*)d_in[8];

  char* ws = (char*)d_ws;
  unsigned* flags  = (unsigned*)(ws + OFF_FLAGS);
  short*    hpack  = (short*)(ws + OFF_HPACK);
  short*    xpack  = (short*)(ws + OFF_XPACK);
  short*    wpack  = (short*)(ws + OFF_WPACK);
  float*    bias   = (float*)(ws + OFF_BIAS);
  float*    out    = (float*)d_out;

  hipMemsetAsync(d_ws, 0, ZERO_BYTES, stream);   // flags + hpack (h0 = 0)
  pack_x_kernel<<<8192, 256, 0, stream>>>(x, xpack);
  pack_w_kernel<<<6144, 256, 0, stream>>>(wih_f, whh_f, wih_b, whh_b, wpack);
  pack_bias_kernel<<<32, 256, 0, stream>>>(bih_f, bhh_f, bih_b, bhh_b, bias);
  lstm_main<<<512, 256, 0, stream>>>(xpack, wpack, bias, hpack, flags, out);
}

// Round 3
// 3560.139 us; speedup vs baseline: 2.5849x; 2.5849x over previous
//
#include <hip/hip_runtime.h>

typedef __attribute__((ext_vector_type(8))) short short8;
typedef __attribute__((ext_vector_type(4))) float f32x4;

#define TT 512
#define II 512
#define HH 1024

// workspace layout (bytes)
#define OFF_FLAGS  0u          // dense: (dir*64+jgrp)*4+wv dwords = 2 KB used
#define OFF_HPACK  8192u       // 2 parity x 2 dir x 8192 frag x 16 B = 524288
#define OFF_XPACK  532480u     // 512 t x 4096 frag x 16 B = 33554432
#define OFF_WPACK  34086912u   // 2 dir x 256 cg x 48 ks x 64 lane x 16 B = 25165824
#define OFF_BIAS   59252736u   // 2 x 4096 fp32 = 32768
#define ZERO_BYTES 532480u     // flags + hpack (h0 = 0)

__device__ __forceinline__ unsigned short f2bf(float f) {
  unsigned u = __builtin_bit_cast(unsigned, f);
  u += 0x7FFFu + ((u >> 16) & 1u);   // RNE
  return (unsigned short)(u >> 16);
}
__device__ __forceinline__ float sigm(float x) {
  return __fdividef(1.f, 1.f + __expf(-x));
}
__device__ __forceinline__ float tanh_(float x) {
  return 1.f - __fdividef(2.f, __expf(2.f * x) + 1.f);
}

__global__ void pack_x_kernel(const float* __restrict__ x, short* __restrict__ xpack) {
  int g = blockIdx.x * 256 + threadIdx.x;
  int lane = g & 63;
  int mt = (g >> 6) & 3;
  int ks = (g >> 8) & 15;
  int t = g >> 12;
  int b = mt * 16 + (lane & 15);
  int i = ks * 32 + ((lane >> 4) & 3) * 8;
  const float* src = x + ((size_t)b * TT + t) * II + i;
  float4 v0 = *(const float4*)(src);
  float4 v1 = *(const float4*)(src + 4);
  short8 o;
  o[0] = (short)f2bf(v0.x); o[1] = (short)f2bf(v0.y);
  o[2] = (short)f2bf(v0.z); o[3] = (short)f2bf(v0.w);
  o[4] = (short)f2bf(v1.x); o[5] = (short)f2bf(v1.y);
  o[6] = (short)f2bf(v1.z); o[7] = (short)f2bf(v1.w);
  *(short8*)(xpack + (size_t)g * 8) = o;
}

__global__ void pack_w_kernel(const float* __restrict__ wih_f, const float* __restrict__ whh_f,
                              const float* __restrict__ wih_b, const float* __restrict__ whh_b,
                              short* __restrict__ wpack) {
  int g = blockIdx.x * 256 + threadIdx.x;
  int lane = g & 63;
  int gg = g >> 6;
  int dir = gg / 12288;
  int rem = gg - dir * 12288;
  int cg = rem / 48;
  int ks = rem - cg * 48;
  int col = cg * 16 + (lane & 15);
  int k = ks * 32 + ((lane >> 4) & 3) * 8;
  const float* wih = dir ? wih_b : wih_f;
  const float* whh = dir ? whh_b : whh_f;
  const float* src = (k < II) ? (wih + (size_t)col * II + k)
                              : (whh + (size_t)col * HH + (k - II));
  float4 v0 = *(const float4*)(src);
  float4 v1 = *(const float4*)(src + 4);
  short8 o;
  o[0] = (short)f2bf(v0.x); o[1] = (short)f2bf(v0.y);
  o[2] = (short)f2bf(v0.z); o[3] = (short)f2bf(v0.w);
  o[4] = (short)f2bf(v1.x); o[5] = (short)f2bf(v1.y);
  o[6] = (short)f2bf(v1.z); o[7] = (short)f2bf(v1.w);
  *(short8*)(wpack + (size_t)g * 8) = o;
}

__global__ void pack_bias_kernel(const float* __restrict__ bif, const float* __restrict__ bhf,
                                 const float* __restrict__ bib, const float* __restrict__ bhb,
                                 float* __restrict__ bias) {
  int g = blockIdx.x * 256 + threadIdx.x;
  int dir = g >> 12, n = g & 4095;
  bias[g] = dir ? (bib[n] + bhb[n]) : (bif[n] + bhf[n]);
}

// 128 blocks x 256 threads (R1 structure). block -> (dir = blk&1, jgrp = blk>>1).
// 4 waves split K. B panels persist in regs. c state in regs.
//
// R3 changes vs R1:
//  - NO acquire fence / buffer_inv. h loads are device-scope (sc1) inline-asm
//    global_load_dwordx4 -> per-load coherence; XCD L2 stays valid so xpack
//    re-reads are L2 hits every step.
//  - dense flag array: dword (dir*64+jgrp)*4+wv. A wave's 64-producer wait-set
//    is 64 CONSECUTIVE dwords (4 lines/poll instead of 64).
//  - all 32 h loads issued up front, ONE s_waitcnt vmcnt(0) + sched_barrier(0)
//    (one MALL latency per step instead of two).
// Sync topology unchanged: union of the 4 waves' wait-sets = all 64 producers,
// h-stores stay behind the single __syncthreads, so the t+1-overwrite-vs-t-read
// hazard is excluded exactly as before.
__launch_bounds__(256, 1)
__global__ void lstm_main(const short* __restrict__ xpack, const short* __restrict__ wpack,
                          const float* __restrict__ bias, short* __restrict__ hpack,
                          unsigned* __restrict__ flags, float* __restrict__ out) {
  __shared__ float red[2 * 16 * 64 * 17];   // [par][wv*4+gg][row][17] = 136 KB

  const int tid = threadIdx.x;
  const int wv = tid >> 6, lane = tid & 63;
  const int blk = blockIdx.x;
  const int dir = blk & 1, jgrp = blk >> 1;
  const int w4 = wv * 4, w8 = wv * 8;

  // ---- preload B fragments (persist across the whole time loop) ----
  short8 bfr[4][12];
  {
    const short8* wp = (const short8*)wpack;
    #pragma unroll
    for (int gg = 0; gg < 4; ++gg) {
      size_t base = ((size_t)(dir * 256 + gg * 64 + jgrp) * 48) * 64 + lane;
      #pragma unroll
      for (int i = 0; i < 4; ++i)
        bfr[gg][i] = wp[base + (size_t)(w4 + i) * 64];
      #pragma unroll
      for (int i = 0; i < 8; ++i)
        bfr[gg][4 + i] = wp[base + (size_t)(16 + w8 + i) * 64];
    }
  }

  const short8* xp8 = (const short8*)xpack;
  const short8* hp8 = (const short8*)hpack;

  // elementwise mapping: thread -> (j0 = jgrp*16 + 2*(tid&7), b in {tid>>3, tid>>3 + 32})
  const int jp = tid & 7, brow = tid >> 3;
  const int j0 = jgrp * 16 + jp * 2;
  float b4[4][2];
  #pragma unroll
  for (int g = 0; g < 4; ++g) {
    b4[g][0] = bias[dir * 4096 + g * 1024 + j0];
    b4[g][1] = bias[dir * 4096 + g * 1024 + j0 + 1];
  }
  float c_reg[2][2] = {{0.f, 0.f}, {0.f, 0.f}};

  // dense flags: producer wave wv of block (dir,jgrp) owns dword (dir*64+jgrp)*4+wv.
  // consumer wave wv polls producers jgrp_p in [16wv,16wv+16) x 4 waves =
  // 64 consecutive dwords starting at (dir*64+16wv)*4 — lane-parallel, 4 lines.
  unsigned* myflag = flags + (size_t)(dir * 64 + jgrp) * 4 + wv;
  const unsigned* wflag = flags + (size_t)(dir * 64 + wv * 16) * 4 + lane;

  for (int t = 0; t < TT; ++t) {
    const int par = t & 1;
    const int t_x = dir ? (TT - 1 - t) : t;

    f32x4 acc[4][4];
    #pragma unroll
    for (int gg = 0; gg < 4; ++gg)
      #pragma unroll
      for (int mt = 0; mt < 4; ++mt) acc[gg][mt] = (f32x4){0.f, 0.f, 0.f, 0.f};

    {  // x-part: batch 16 A-fragment loads, then MFMA (off the inter-block path)
      const short8* xbase = xp8 + (size_t)t_x * 4096;
      short8 xa[16];
      #pragma unroll
      for (int i = 0; i < 4; ++i) {
        const short8* ab = xbase + (w4 + i) * 256;
        xa[4 * i + 0] = ab[lane];
        xa[4 * i + 1] = ab[64 + lane];
        xa[4 * i + 2] = ab[128 + lane];
        xa[4 * i + 3] = ab[192 + lane];
      }
      #pragma unroll
      for (int i = 0; i < 4; ++i)
        #pragma unroll
        for (int gg = 0; gg < 4; ++gg) {
          acc[gg][0] = __builtin_amdgcn_mfma_f32_16x16x32_bf16(xa[4 * i + 0], bfr[gg][i], acc[gg][0], 0, 0, 0);
          acc[gg][1] = __builtin_amdgcn_mfma_f32_16x16x32_bf16(xa[4 * i + 1], bfr[gg][i], acc[gg][1], 0, 0, 0);
          acc[gg][2] = __builtin_amdgcn_mfma_f32_16x16x32_bf16(xa[4 * i + 2], bfr[gg][i], acc[gg][2], 0, 0, 0);
          acc[gg][3] = __builtin_amdgcn_mfma_f32_16x16x32_bf16(xa[4 * i + 3], bfr[gg][i], acc[gg][3], 0, 0, 0);
        }
    }

    // ---- per-wave wait: 64 consecutive flag dwords (4 lines), lane-parallel ----
    if (t) {
      unsigned v = __hip_atomic_load(wflag, __ATOMIC_RELAXED, __HIP_MEMORY_SCOPE_AGENT);
      while (!__all((int)(v >= (unsigned)t))) {
        __builtin_amdgcn_s_sleep(1);
        v = __hip_atomic_load(wflag, __ATOMIC_RELAXED, __HIP_MEMORY_SCOPE_AGENT);
      }
      // no fence: freshness is per-load (sc1) below; L2 stays valid for xpack
    }

    {  // h-part: issue ALL 32 device-scope loads, one vmcnt(0), then 128 MFMAs
      const short8* hbase = hp8 + (size_t)(par * 2 + dir) * 8192;
      short8 ha[32];
      #pragma unroll
      for (int j = 0; j < 8; ++j) {
        const short8* aj = hbase + (w8 + j) * 256 + lane;
        asm volatile(
            "global_load_dwordx4 %0, %4, off sc1\n\t"
            "global_load_dwordx4 %1, %4, off offset:1024 sc1\n\t"
            "global_load_dwordx4 %2, %4, off offset:2048 sc1\n\t"
            "global_load_dwordx4 %3, %4, off offset:3072 sc1"
            : "=v"(ha[4 * j + 0]), "=v"(ha[4 * j + 1]),
              "=v"(ha[4 * j + 2]), "=v"(ha[4 * j + 3])
            : "v"(aj));
      }
      asm volatile("s_waitcnt vmcnt(0)" ::: "memory");
      __builtin_amdgcn_sched_barrier(0);   // rule #18: pin MFMAs below the wait
      #pragma unroll
      for (int j = 0; j < 8; ++j)
        #pragma unroll
        for (int gg = 0; gg < 4; ++gg) {
          const short8 bf = bfr[gg][4 + j];
          acc[gg][0] = __builtin_amdgcn_mfma_f32_16x16x32_bf16(ha[4 * j + 0], bf, acc[gg][0], 0, 0, 0);
          acc[gg][1] = __builtin_amdgcn_mfma_f32_16x16x32_bf16(ha[4 * j + 1], bf, acc[gg][1], 0, 0, 0);
          acc[gg][2] = __builtin_amdgcn_mfma_f32_16x16x32_bf16(ha[4 * j + 2], bf, acc[gg][2], 0, 0, 0);
          acc[gg][3] = __builtin_amdgcn_mfma_f32_16x16x32_bf16(ha[4 * j + 3], bf, acc[gg][3], 0, 0, 0);
        }
    }

    {  // partial sums -> LDS (parity buffer) for cross-wave reduction
      int q = lane >> 4, cl = lane & 15;
      float* rb = red + (size_t)par * (16 * 64 * 17);
      #pragma unroll
      for (int gg = 0; gg < 4; ++gg)
        #pragma unroll
        for (int mt = 0; mt < 4; ++mt)
          #pragma unroll
          for (int r = 0; r < 4; ++r)
            rb[((w4 + gg) * 64 + (mt * 16 + q * 4 + r)) * 17 + cl] = acc[gg][mt][r];
    }
    __syncthreads();   // the ONLY barrier per step (red write -> read)

    // ---- elementwise LSTM update; c in registers ----
    const float* rbr = red + (size_t)par * (16 * 64 * 17);
    float hv4[2][2];
    #pragma unroll
    for (int bb = 0; bb < 2; ++bb) {
      int b = brow + 32 * bb;
      float g4[4][2];
      #pragma unroll
      for (int g = 0; g < 4; ++g) { g4[g][0] = b4[g][0]; g4[g][1] = b4[g][1]; }
      #pragma unroll
      for (int w = 0; w < 4; ++w)
        #pragma unroll
        for (int g = 0; g < 4; ++g) {
          const float* rp = &rbr[((w * 4 + g) * 64 + b) * 17 + jp * 2];
          g4[g][0] += rp[0];
          g4[g][1] += rp[1];
        }
      #pragma unroll
      for (int jj = 0; jj < 2; ++jj) {
        float cn = sigm(g4[1][jj]) * c_reg[bb][jj] + sigm(g4[0][jj]) * tanh_(g4[2][jj]);
        c_reg[bb][jj] = cn;
        hv4[bb][jj] = sigm(g4[3][jj]) * tanh_(cn);
      }
      // h -> hpack (A-frag layout, next parity) as one packed int, sc1 write-through
      int lane_ = (b & 15) | (((j0 >> 3) & 3) << 4);
      size_t hidx = (size_t)((par ^ 1) * 2 + dir) * 65536 +
                    (size_t)(((j0 >> 5) * 4 + (b >> 4)) * 64 + lane_) * 8 + (j0 & 7);
      unsigned hv = (unsigned)f2bf(hv4[bb][0]) | ((unsigned)f2bf(hv4[bb][1]) << 16);
      __hip_atomic_store((unsigned*)(hpack + hidx), hv, __ATOMIC_RELAXED, __HIP_MEMORY_SCOPE_AGENT);
    }

    // ---- per-wave publish: drain OWN stores, then flag. No barrier. ----
    asm volatile("s_waitcnt vmcnt(0)" ::: "memory");
    if (lane == 0)
      __hip_atomic_store(myflag, (unsigned)(t + 1), __ATOMIC_RELAXED, __HIP_MEMORY_SCOPE_AGENT);
    asm volatile("" ::: "memory");   // keep out-stores below the flag

    // ---- out stores AFTER publish (retire during the next step's wait) ----
    #pragma unroll
    for (int bb = 0; bb < 2; ++bb) {
      int b = brow + 32 * bb;
      *(float2*)(out + ((size_t)(b * TT + t) * 2 + dir) * 1024 + j0) =
          make_float2(hv4[bb][0], hv4[bb][1]);
    }
    if (t == TT - 1) {
      #pragma unroll
      for (int bb = 0; bb < 2; ++bb) {
        int b = brow + 32 * bb;
        size_t base2 = (size_t)64 * TT * 2048;
        *(float2*)(out + base2 + (size_t)dir * 131072 + (size_t)b * 1024 + j0) =
            make_float2(hv4[bb][0], hv4[bb][1]);
        *(float2*)(out + base2 + (size_t)dir * 131072 + 65536 + (size_t)b * 1024 + j0) =
            make_float2(c_reg[bb][0], c_reg[bb][1]);
      }
    }
  }
}

extern "C" void kernel_launch(void* const* d_in, const int* in_sizes, int n_in,
                              void* d_out, int out_size, void* d_ws, size_t ws_size,
                              hipStream_t stream) {
  const float* x     = (const float*)d_in[0];
  const float* wih_f = (const float*)d_in[1];
  const float* whh_f = (const float*)d_in[2];
  const float* bih_f = (const float*)d_in[3];
  const float* bhh_f = (const float*)d_in[4];
  const float* wih_b = (const float*)d_in[5];
  const float* whh_b = (const float*)d_in[6];
  const float* bih_b = (const float*)d_in[7];
  const float* bhh_b = (const float*)d_in[8];

  char* ws = (char*)d_ws;
  unsigned* flags  = (unsigned*)(ws + OFF_FLAGS);
  short*    hpack  = (short*)(ws + OFF_HPACK);
  short*    xpack  = (short*)(ws + OFF_XPACK);
  short*    wpack  = (short*)(ws + OFF_WPACK);
  float*    bias   = (float*)(ws + OFF_BIAS);
  float*    out    = (float*)d_out;

  hipMemsetAsync(d_ws, 0, ZERO_BYTES, stream);   // flags + hpack (h0 = 0)
  pack_x_kernel<<<8192, 256, 0, stream>>>(x, xpack);
  pack_w_kernel<<<6144, 256, 0, stream>>>(wih_f, whh_f, wih_b, whh_b, wpack);
  pack_bias_kernel<<<32, 256, 0, stream>>>(bih_f, bhh_f, bih_b, bhh_b, bias);
  lstm_main<<<128, 256, 0, stream>>>(xpack, wpack, bias, hpack, flags, out);
}